// Round 1
// baseline (489.655 us; speedup 1.0000x reference)
//
#include <hip/hip_runtime.h>
#include <stdint.h>

#define NLBL 2

// ---------------------------------------------------------------------------
// Kernel 1: Wf[v] = token_mask[v] * (W_cls @ W_embed)[:, v], stored interleaved
// as float2 so any v index is 8B-aligned.
// Block = 256 threads; each block covers 64 v's; the 4 waves split the h-range.
// Wave lanes read 64 consecutive floats of a W_embed row -> coalesced 256B.
// ---------------------------------------------------------------------------
__global__ __launch_bounds__(256) void fuse_weights_kernel(
    const float* __restrict__ Wemb,   // [H][V]
    const float* __restrict__ tmask,  // [V]
    const float* __restrict__ Wcls,   // [2][H]
    float2* __restrict__ wf2,         // [V]
    int V, int H)
{
    __shared__ float sW0[1024];
    __shared__ float sW1[1024];
    __shared__ float part[4][64][2];

    for (int i = threadIdx.x; i < H; i += blockDim.x) {
        sW0[i] = Wcls[i];
        sW1[i] = Wcls[H + i];
    }
    __syncthreads();

    const int vl = threadIdx.x & 63;   // lane within wave
    const int hg = threadIdx.x >> 6;   // wave id 0..3
    const int v  = blockIdx.x * 64 + vl;

    float a0 = 0.f, a1 = 0.f;
    if (v < V) {
        for (int h = hg; h < H; h += 4) {
            float w = Wemb[(size_t)h * (size_t)V + v];
            a0 = fmaf(w, sW0[h], a0);
            a1 = fmaf(w, sW1[h], a1);
        }
    }
    part[hg][vl][0] = a0;
    part[hg][vl][1] = a1;
    __syncthreads();

    if (hg == 0 && v < V) {
        float r0 = (part[0][vl][0] + part[1][vl][0]) + (part[2][vl][0] + part[3][vl][0]);
        float r1 = (part[0][vl][1] + part[1][vl][1]) + (part[2][vl][1] + part[3][vl][1]);
        float m = tmask[v];
        wf2[v] = make_float2(r0 * m, r1 * m);
    }
}

// ---------------------------------------------------------------------------
// Kernel 2: one block per token. Stream the token's vocab row (aligned float4
// body + scalar head/tail because V is odd) and accumulate:
//   s  = sum_v e[v]
//   d0 = sum_v e[v] * Wf[0][v]
//   d1 = sum_v e[v] * Wf[1][v]
// logits = d/s + b.
// ---------------------------------------------------------------------------
__global__ __launch_bounds__(256) void token_logits_kernel(
    const float* __restrict__ emb,   // [T][V]
    const float2* __restrict__ wf2,  // [V] interleaved {w0, w1}
    const float* __restrict__ bcls,  // [2]
    float* __restrict__ out,         // [T][2]
    int V)
{
    const int t   = blockIdx.x;
    const int tid = threadIdx.x;
    const float* row = emb + (size_t)t * (size_t)V;

    // misalignment of row start in floats (emb base is 16B-aligned from the
    // harness; compute from the actual pointer to be safe)
    const int mis  = (int)((((uintptr_t)row) >> 2) & 3);
    const int head = (4 - mis) & 3;

    float s = 0.f, d0 = 0.f, d1 = 0.f;

    // head scalars (0..3 elements)
    if (tid < head) {
        float e = row[tid];
        float2 w = wf2[tid];
        s += e;
        d0 = fmaf(e, w.x, d0);
        d1 = fmaf(e, w.y, d1);
    }

    const int nbody     = (V - head) >> 2;
    const int tailStart = head + (nbody << 2);
    const int ntail     = V - tailStart;   // 0..3

    // tail scalars
    if (tid < ntail) {
        int v = tailStart + tid;
        float e = row[v];
        float2 w = wf2[v];
        s += e;
        d0 = fmaf(e, w.x, d0);
        d1 = fmaf(e, w.y, d1);
    }

    // aligned float4 body
    const float4* __restrict__ e4 = (const float4*)(row + head);
    for (int j = tid; j < nbody; j += 256) {
        float4 ev = e4[j];
        int v = head + (j << 2);
        float2 w0 = wf2[v];
        float2 w1 = wf2[v + 1];
        float2 w2 = wf2[v + 2];
        float2 w3 = wf2[v + 3];
        s += (ev.x + ev.y) + (ev.z + ev.w);
        d0 = fmaf(ev.x, w0.x, d0);
        d0 = fmaf(ev.y, w1.x, d0);
        d0 = fmaf(ev.z, w2.x, d0);
        d0 = fmaf(ev.w, w3.x, d0);
        d1 = fmaf(ev.x, w0.y, d1);
        d1 = fmaf(ev.y, w1.y, d1);
        d1 = fmaf(ev.z, w2.y, d1);
        d1 = fmaf(ev.w, w3.y, d1);
    }

    // reduce (s, d0, d1) across the block: wave shuffle then LDS across waves
    #pragma unroll
    for (int off = 32; off > 0; off >>= 1) {
        s  += __shfl_xor(s,  off);
        d0 += __shfl_xor(d0, off);
        d1 += __shfl_xor(d1, off);
    }

    __shared__ float red[4][3];
    const int lane = tid & 63;
    const int wid  = tid >> 6;
    if (lane == 0) {
        red[wid][0] = s;
        red[wid][1] = d0;
        red[wid][2] = d1;
    }
    __syncthreads();

    if (tid == 0) {
        float S  = (red[0][0] + red[1][0]) + (red[2][0] + red[3][0]);
        float D0 = (red[0][1] + red[1][1]) + (red[2][1] + red[3][1]);
        float D1 = (red[0][2] + red[1][2]) + (red[2][2] + red[3][2]);
        out[2 * t]     = D0 / S + bcls[0];
        out[2 * t + 1] = D1 / S + bcls[1];
    }
}

extern "C" void kernel_launch(void* const* d_in, const int* in_sizes, int n_in,
                              void* d_out, int out_size, void* d_ws, size_t ws_size,
                              hipStream_t stream) {
    const float* emb   = (const float*)d_in[0];   // [B,S,V] f32
    // d_in[1]: attention_masks (unused by the math)
    const float* Wemb  = (const float*)d_in[2];   // [H,V] f32
    const float* tmask = (const float*)d_in[3];   // [V] f32
    const float* Wcls  = (const float*)d_in[4];   // [2,H] f32
    const float* bcls  = (const float*)d_in[5];   // [2] f32
    float* out = (float*)d_out;

    const int V = in_sizes[3];                    // 50265
    const int T = in_sizes[1];                    // B*S = 8192
    const int H = in_sizes[2] / V;                // 768

    float2* wf2 = (float2*)d_ws;                  // V float2 = 402 KB scratch

    // Kernel 1: fused classifier-through-embedding weight (2 x V)
    int blocks1 = (V + 63) / 64;
    fuse_weights_kernel<<<blocks1, 256, 0, stream>>>(Wemb, tmask, Wcls, wf2, V, H);

    // Kernel 2: per-token row sum + two dots + normalize + bias
    token_logits_kernel<<<T, 256, 0, stream>>>(emb, wf2, bcls, out, V);
}